// Round 2
// baseline (76.809 us; speedup 1.0000x reference)
//
#include <hip/hip_runtime.h>

// GaussianKernelConv: out[b,n,p] = mean_k exp(-||x_bnk - kp_p||^2 / (2 sigma^2))
// B=8, N=8192, K=32, C=3, P=16 (sizes derived from in_sizes at launch).
//
// exp(-d/(2s^2)) = exp2( s*||x||^2 + s*||kp||^2 + (-2s)*(x . kp) ),
//   s = -log2(e)/(2 sigma^2)  -> per (k,p) cell: 3 fma + 1 add + v_exp_f32 + acc.
//
// 4 threads per (b,n) row, 8 k's each -> 262144 threads (4096 waves, 16/CU).
// Reduce over the 4 lanes via __shfl_xor(1),__shfl_xor(2); each lane writes
// one float4 of the 16 outputs -> coalesced 64B per row.

namespace {
constexpr int KN = 32;          // neighbors per point
constexpr int CC = 3;           // coords
constexpr int PP = 16;          // kernel points
constexpr int CHUNK = 8;        // k's per thread
constexpr int TPR = KN / CHUNK; // 4 threads per row
}

__global__ __launch_bounds__(256) void gkc_kernel(
    const float* __restrict__ nb,     // (rows, K, C) f32
    const float* __restrict__ kp,     // (P, C) f32
    const float* __restrict__ sigmap, // scalar
    float* __restrict__ out,          // (rows, P) f32
    int nrows)
{
    const int t = blockIdx.x * 256 + threadIdx.x;
    const int row = t >> 2;
    const int chunk = t & 3;
    if (row >= nrows) return;

    const float sigma = sigmap[0];
    const float s = -1.44269504088896340736f / (2.0f * sigma * sigma); // exp2 scale
    const float W = -2.0f * s;

    // Per-p weight table. Addresses are thread-invariant compile-time indices
    // -> compiler scalarizes to s_load; values live in SGPRs.
    float kx[PP], ky[PP], kz[PP], cp[PP];
#pragma unroll
    for (int p = 0; p < PP; ++p) {
        const float a = kp[p * 3 + 0];
        const float b = kp[p * 3 + 1];
        const float c = kp[p * 3 + 2];
        kx[p] = a;
        ky[p] = b;
        kz[p] = c;
        cp[p] = s * fmaf(a, a, fmaf(b, b, c * c)); // s*||kp||^2
    }

    // Load this thread's 8 neighbors: 24 contiguous floats = 6x float4
    // (row*384B + chunk*96B -> 16B aligned).
    const float4* src =
        reinterpret_cast<const float4*>(nb + (size_t)row * (KN * CC) + chunk * (CHUNK * CC));
    float4 v[6];
#pragma unroll
    for (int i = 0; i < 6; ++i) v[i] = src[i];
    float x[24];
#pragma unroll
    for (int i = 0; i < 6; ++i) {
        x[4 * i + 0] = v[i].x;
        x[4 * i + 1] = v[i].y;
        x[4 * i + 2] = v[i].z;
        x[4 * i + 3] = v[i].w;
    }

    float acc[PP];
#pragma unroll
    for (int p = 0; p < PP; ++p) acc[p] = 0.0f;

#pragma unroll
    for (int k = 0; k < CHUNK; ++k) {
        const float x0 = x[3 * k + 0];
        const float x1 = x[3 * k + 1];
        const float x2 = x[3 * k + 2];
        const float t0 = s * fmaf(x0, x0, fmaf(x1, x1, x2 * x2)); // s*||x||^2
        const float y0 = W * x0;
        const float y1 = W * x1;
        const float y2 = W * x2;
#pragma unroll
        for (int p = 0; p < PP; ++p) {
            const float arg =
                fmaf(y2, kz[p], fmaf(y1, ky[p], fmaf(y0, kx[p], t0 + cp[p])));
            acc[p] += __builtin_amdgcn_exp2f(arg); // native v_exp_f32
        }
    }

    // Reduce the 4 per-row lanes (lane bits 0,1): quad-perm DPP shuffles.
#pragma unroll
    for (int p = 0; p < PP; ++p) {
        acc[p] += __shfl_xor(acc[p], 1);
        acc[p] += __shfl_xor(acc[p], 2);
    }

    // Lane `chunk` writes outputs p = 4*chunk .. 4*chunk+3 (static indices only;
    // runtime 4-way select via cndmask, never runtime array indexing - rule #20).
    const bool lo = (chunk & 2) == 0;
    const bool even = (chunk & 1) == 0;
    const float o0 = lo ? (even ? acc[0] : acc[4]) : (even ? acc[8] : acc[12]);
    const float o1 = lo ? (even ? acc[1] : acc[5]) : (even ? acc[9] : acc[13]);
    const float o2 = lo ? (even ? acc[2] : acc[6]) : (even ? acc[10] : acc[14]);
    const float o3 = lo ? (even ? acc[3] : acc[7]) : (even ? acc[11] : acc[15]);

    const float inv = 1.0f / (float)KN;
    float4 o;
    o.x = o0 * inv;
    o.y = o1 * inv;
    o.z = o2 * inv;
    o.w = o3 * inv;
    reinterpret_cast<float4*>(out + (size_t)row * PP + chunk * 4)[0] = o;
}

extern "C" void kernel_launch(void* const* d_in, const int* in_sizes, int n_in,
                              void* d_out, int out_size, void* d_ws, size_t ws_size,
                              hipStream_t stream) {
    const float* nb = (const float*)d_in[0];
    const float* kp = (const float*)d_in[1];
    const float* sg = (const float*)d_in[2];
    float* out = (float*)d_out;

    const int nrows = in_sizes[0] / (KN * CC); // B*N = 65536
    const int threads = nrows * TPR;
    const int block = 256;
    const int grid = (threads + block - 1) / block;
    gkc_kernel<<<grid, block, 0, stream>>>(nb, kp, sg, out, nrows);
}

// Round 3
// 75.527 us; speedup vs baseline: 1.0170x; 1.0170x over previous
//
#include <hip/hip_runtime.h>

// GaussianKernelConv: out[b,n,p] = mean_k exp(-||x_bnk - kp_p||^2 / (2 sigma^2))
// B=8, N=8192, K=32, C=3, P=16.
//
// exp(-d/(2s^2)) = exp2( s*||x||^2 + s*||kp||^2 + (-2s)*(x . kp) ),
//   s = -log2(e)/(2 sigma^2).
//
// Structure (low-register, packed):
//  - 4 threads per (b,n) row, 8 k's each (262144 threads, 4096 waves).
//  - p is the OUTER loop: only one kernel point (4 uniform scalars) live at a
//    time; per-k packed pairs Y0..Y2,T0 (16 float2 = 32 VGPR) + acc[16].
//  - k-pairs packed as float2 -> v_pk_fma_f32 (2x f32 FMA rate).
//  - reduce 4 lanes/row via __shfl_xor(1/2); float4 coalesced store.

namespace {
constexpr int KN = 32;          // neighbors per point
constexpr int CC = 3;           // coords
constexpr int PP = 16;          // kernel points
constexpr int CHUNK = 8;        // k's per thread
constexpr int TPR = KN / CHUNK; // 4 threads per row
typedef float f32x2 __attribute__((ext_vector_type(2)));
}

__global__ __launch_bounds__(256) void gkc_kernel(
    const float* __restrict__ nb,     // (rows, K, C) f32
    const float* __restrict__ kp,     // (P, C) f32
    const float* __restrict__ sigmap, // scalar
    float* __restrict__ out,          // (rows, P) f32
    int nrows)
{
    const int t = blockIdx.x * 256 + threadIdx.x;
    const int row = t >> 2;
    const int chunk = t & 3;
    if (row >= nrows) return;

    const float sigma = sigmap[0];
    const float s = -1.44269504088896340736f / (2.0f * sigma * sigma); // exp2 scale
    const float W = -2.0f * s;

    // Load this thread's 8 neighbors: 24 contiguous floats = 6x float4
    // (row*384B + chunk*96B -> 16B aligned).
    const float4* src =
        reinterpret_cast<const float4*>(nb + (size_t)row * (KN * CC) + chunk * (CHUNK * CC));
    float x[24];
#pragma unroll
    for (int i = 0; i < 6; ++i) {
        const float4 v = src[i];
        x[4 * i + 0] = v.x;
        x[4 * i + 1] = v.y;
        x[4 * i + 2] = v.z;
        x[4 * i + 3] = v.w;
    }

    // Packed per-k-pair precompute: Y = (-2s)*x, T0 = s*||x||^2.
    f32x2 Y0[4], Y1[4], Y2[4], T0[4];
#pragma unroll
    for (int j = 0; j < 4; ++j) {
        const float xa0 = x[6 * j + 0], xa1 = x[6 * j + 1], xa2 = x[6 * j + 2];
        const float xb0 = x[6 * j + 3], xb1 = x[6 * j + 4], xb2 = x[6 * j + 5];
        Y0[j] = f32x2{W * xa0, W * xb0};
        Y1[j] = f32x2{W * xa1, W * xb1};
        Y2[j] = f32x2{W * xa2, W * xb2};
        T0[j] = f32x2{s * fmaf(xa0, xa0, fmaf(xa1, xa1, xa2 * xa2)),
                      s * fmaf(xb0, xb0, fmaf(xb1, xb1, xb2 * xb2))};
    }

    float acc[PP];
#pragma unroll
    for (int p = 0; p < PP; ++p) {
        // One kernel point at a time: uniform scalars -> SGPRs, tiny live set.
        const float ka = kp[3 * p + 0];
        const float kb = kp[3 * p + 1];
        const float kc = kp[3 * p + 2];
        const float cpp = s * fmaf(ka, ka, fmaf(kb, kb, kc * kc)); // s*||kp||^2
        const f32x2 kx2 = {ka, ka}, ky2 = {kb, kb}, kz2 = {kc, kc}, cp2 = {cpp, cpp};

        f32x2 a2 = {0.0f, 0.0f};
#pragma unroll
        for (int j = 0; j < 4; ++j) {
            const f32x2 arg = __builtin_elementwise_fma(Y2[j], kz2,
                              __builtin_elementwise_fma(Y1[j], ky2,
                              __builtin_elementwise_fma(Y0[j], kx2, T0[j] + cp2)));
            a2 += f32x2{__builtin_amdgcn_exp2f(arg.x), __builtin_amdgcn_exp2f(arg.y)};
        }
        acc[p] = a2.x + a2.y;
    }

    // Reduce the 4 per-row lanes (lane bits 0,1): quad-perm DPP shuffles.
#pragma unroll
    for (int p = 0; p < PP; ++p) {
        acc[p] += __shfl_xor(acc[p], 1);
        acc[p] += __shfl_xor(acc[p], 2);
    }

    // Lane `chunk` writes outputs p = 4*chunk .. 4*chunk+3 (static indices only;
    // runtime 4-way select via cndmask, never runtime array indexing).
    const bool lo = (chunk & 2) == 0;
    const bool even = (chunk & 1) == 0;
    const float o0 = lo ? (even ? acc[0] : acc[4]) : (even ? acc[8] : acc[12]);
    const float o1 = lo ? (even ? acc[1] : acc[5]) : (even ? acc[9] : acc[13]);
    const float o2 = lo ? (even ? acc[2] : acc[6]) : (even ? acc[10] : acc[14]);
    const float o3 = lo ? (even ? acc[3] : acc[7]) : (even ? acc[11] : acc[15]);

    const float inv = 1.0f / (float)KN;
    float4 o;
    o.x = o0 * inv;
    o.y = o1 * inv;
    o.z = o2 * inv;
    o.w = o3 * inv;
    reinterpret_cast<float4*>(out + (size_t)row * PP + chunk * 4)[0] = o;
}

extern "C" void kernel_launch(void* const* d_in, const int* in_sizes, int n_in,
                              void* d_out, int out_size, void* d_ws, size_t ws_size,
                              hipStream_t stream) {
    const float* nb = (const float*)d_in[0];
    const float* kp = (const float*)d_in[1];
    const float* sg = (const float*)d_in[2];
    float* out = (float*)d_out;

    const int nrows = in_sizes[0] / (KN * CC); // B*N = 65536
    const int threads = nrows * TPR;
    const int block = 256;
    const int grid = (threads + block - 1) / block;
    gkc_kernel<<<grid, block, 0, stream>>>(nb, kp, sg, out, nrows);
}